// Round 2
// baseline (285.704 us; speedup 1.0000x reference)
//
#include <hip/hip_runtime.h>

#define S_LEN 2048
#define NHQ 8
#define NKV 2
#define HD 256
#define KVB 32

typedef __attribute__((ext_vector_type(8))) short bf16x8;
typedef __attribute__((ext_vector_type(4))) short bf16x4;
typedef __attribute__((ext_vector_type(4))) float f32x4;
typedef __attribute__((ext_vector_type(16))) float f32x16;
typedef __attribute__((ext_vector_type(4))) unsigned u32x4;

__device__ __forceinline__ short f2bf(float f) {
    unsigned u = __builtin_bit_cast(unsigned, f);
    u += 0x7FFFu + ((u >> 16) & 1u);
    return (short)(u >> 16);
}
__device__ __forceinline__ float bf2f(short s) {
    unsigned u = ((unsigned)(unsigned short)s) << 16;
    return __builtin_bit_cast(float, u);
}
__device__ __forceinline__ unsigned cvtpk(float a, float b) {
    unsigned r;
    asm("v_cvt_pk_bf16_f32 %0, %1, %2" : "=v"(r) : "v"(a), "v"(b));
    return r;
}
__device__ __forceinline__ void gload16(const short* g, short* l) {
    __builtin_amdgcn_global_load_lds((const __attribute__((address_space(1))) unsigned*)g,
                                     (__attribute__((address_space(3))) unsigned*)l, 16, 0, 0);
}
__device__ __forceinline__ float bperm(int srclane, float v) {
    return __builtin_bit_cast(float,
        __builtin_amdgcn_ds_bpermute(srclane * 4, __builtin_bit_cast(int, v)));
}

// ---------------- fp32 -> bf16 convert ----------------
__global__ __launch_bounds__(256) void cvt_kernel(const float* __restrict__ in,
                                                  short* __restrict__ out, int n) {
    int i = (blockIdx.x * 256 + threadIdx.x) * 4;
    if (i + 3 < n) {
        float4 f = *(const float4*)(in + i);
        bf16x4 o;
        o[0] = f2bf(f.x); o[1] = f2bf(f.y); o[2] = f2bf(f.z); o[3] = f2bf(f.w);
        *(bf16x4*)(out + i) = o;
    }
}

// ---------------- GEMM: C[MxN] = A[MxK](bf16) @ B[KxN](bf16) ----------------
template<int WRITE_BF16>
__global__ __launch_bounds__(256) void gemm_kernel(const short* __restrict__ A,
                                                   const short* __restrict__ B,
                                                   void* __restrict__ Cv,
                                                   int M, int N, int K) {
    __shared__ short As[64 * 32];
    __shared__ short Bs[64 * 32];   // transposed: Bs[n][k]
    const int t = threadIdx.x;
    const int lane = t & 63, wid = t >> 6;
    const int lr = lane & 15, lg = lane >> 4;
    const int m0 = blockIdx.y * 64, n0 = blockIdx.x * 64;
    const int wm = (wid >> 1) * 32, wn = (wid & 1) * 32;

    f32x4 acc[2][2];
    for (int i = 0; i < 2; i++) for (int j = 0; j < 2; j++)
        acc[i][j] = (f32x4){0.f, 0.f, 0.f, 0.f};

    const int ar = t >> 2, ac = (t & 3) * 8;
    const int bn = t & 63, bk0 = (t >> 6) * 8;

    for (int k0 = 0; k0 < K; k0 += 32) {
        __syncthreads();
        *(bf16x8*)&As[ar * 32 + ac] = *(const bf16x8*)&A[(long)(m0 + ar) * K + k0 + ac];
        #pragma unroll
        for (int i = 0; i < 8; i++)
            Bs[bn * 32 + bk0 + i] = B[(long)(k0 + bk0 + i) * N + n0 + bn];
        __syncthreads();
        #pragma unroll
        for (int mi = 0; mi < 2; mi++) {
            bf16x8 af = *(const bf16x8*)&As[(wm + mi * 16 + lr) * 32 + lg * 8];
            #pragma unroll
            for (int ni = 0; ni < 2; ni++) {
                bf16x8 bfr = *(const bf16x8*)&Bs[(wn + ni * 16 + lr) * 32 + lg * 8];
                acc[mi][ni] = __builtin_amdgcn_mfma_f32_16x16x32_bf16(af, bfr, acc[mi][ni], 0, 0, 0);
            }
        }
    }
    #pragma unroll
    for (int mi = 0; mi < 2; mi++)
    #pragma unroll
    for (int ni = 0; ni < 2; ni++)
    #pragma unroll
    for (int r = 0; r < 4; r++) {
        long row = m0 + wm + mi * 16 + lg * 4 + r;
        long col = n0 + wn + ni * 16 + lr;
        float v = acc[mi][ni][r];
        if (WRITE_BF16) ((short*)Cv)[row * N + col] = f2bf(v);
        else            ((float*)Cv)[row * N + col] = v;
    }
}

// ---------------- RMSNorm + partial RoPE (+ optional score prescale) --------
__global__ __launch_bounds__(256) void norm_rope_kernel(
    const short* __restrict__ in, short* __restrict__ out,
    const float* __restrict__ w, const float* __restrict__ cosb,
    const float* __restrict__ sinb, int H, long ob, long oh, long os,
    float scale) {
    int vec = blockIdx.x * 4 + (threadIdx.x >> 6);
    int lane = threadIdx.x & 63;
    int token = vec / H, head = vec % H;
    int b = token / S_LEN, s = token % S_LEN;

    bf16x4 xv = *(const bf16x4*)(in + (long)vec * 256 + lane * 4);
    float x0 = bf2f(xv[0]), x1 = bf2f(xv[1]), x2 = bf2f(xv[2]), x3 = bf2f(xv[3]);
    float ss = x0 * x0 + x1 * x1 + x2 * x2 + x3 * x3;
    #pragma unroll
    for (int m = 1; m < 64; m <<= 1) ss += __shfl_xor(ss, m);
    float inv = rsqrtf(ss * (1.f / 256.f) + 1e-6f);

    float4 wv = *(const float4*)(w + lane * 4);
    float y0 = x0 * inv * (1.f + wv.x);
    float y1 = x1 * inv * (1.f + wv.y);
    float y2 = x2 * inv * (1.f + wv.z);
    float y3 = x3 * inv * (1.f + wv.w);

    if (lane < 16) {
        float2 c = *(const float2*)&cosb[s * 32 + lane * 2];
        float2 sn = *(const float2*)&sinb[s * 32 + lane * 2];
        float a0 = y0 * c.x - y1 * sn.x, b0 = y0 * sn.x + y1 * c.x;
        float a1 = y2 * c.y - y3 * sn.y, b1 = y2 * sn.y + y3 * c.y;
        y0 = a0; y1 = b0; y2 = a1; y3 = b1;
    }
    y0 *= scale; y1 *= scale; y2 *= scale; y3 *= scale;
    long oidx = (long)b * ob + (long)head * oh + (long)s * os + lane * 4;
    bf16x4 o; o[0] = f2bf(y0); o[1] = f2bf(y1); o[2] = f2bf(y2); o[3] = f2bf(y3);
    *(bf16x4*)(out + oidx) = o;
}

// ---------------- V transpose: vf[b][s][kv][d] -> vr[b][kv][d][s] ----------------
__global__ __launch_bounds__(256) void transpose_v_kernel(const short* __restrict__ vf,
                                                          short* __restrict__ vr) {
    __shared__ short tile[64][65];
    int s0 = blockIdx.x * 64, d0 = blockIdx.y * 64;
    int bkv = blockIdx.z; int b = bkv >> 1, kv = bkv & 1;
    int t = threadIdx.x;
    #pragma unroll
    for (int i = 0; i < 16; i++) {
        int flat = i * 256 + t; int si = flat >> 6, di = flat & 63;
        tile[si][di] = vf[(long)(b * S_LEN + s0 + si) * 512 + kv * 256 + d0 + di];
    }
    __syncthreads();
    #pragma unroll
    for (int i = 0; i < 16; i++) {
        int flat = i * 256 + t; int di = flat >> 6, si = flat & 63;
        vr[(long)(bkv * 256 + d0 + di) * S_LEN + s0 + si] = tile[si][di];
    }
}

// ---------------- flash attention (m214-style, 32x32 swapped QK^T) ----------
// block: 128 thr = 2 waves; each wave owns 32 q rows; KV tiles of 32 in LDS.
// Scores pre-scaled by 1/16 (folded into Q).
__global__ __launch_bounds__(128, 2) void flash_kernel(const short* __restrict__ Q,
                                                       const short* __restrict__ Kt,
                                                       const short* __restrict__ Vt,
                                                       short* __restrict__ O) {
    __shared__ short Ks[KVB * 256];   // [key][d] rows 512B, byte ^= (key&7)<<4
    __shared__ short Vs[256 * KVB];   // [d][key] rows 64B,  byte ^= (d&3)<<4

    int idx = blockIdx.x;
    int half = idx >> 8, rem = idx & 255;
    int qtr = rem >> 4;
    int qt = half ? (31 - qtr) : qtr;       // causal work balancing
    int hb = rem & 15, h = hb & 7, b = hb >> 3;
    int kv = h >> 2;
    int t = threadIdx.x, lane = t & 63, w = t >> 6;
    int ln = lane & 31, hi = lane >> 5;
    int q0 = qt * 64 + w * 32;
    int qg = q0 + ln;                        // this lane's q row (score column)

    // Q fragments in registers: Q[q=ln][dc*16 + hi*8 + e]
    bf16x8 qf[16];
    {
        const short* qrow = Q + ((long)(b * S_LEN + qg) * NHQ + h) * HD + hi * 8;
        #pragma unroll
        for (int dc = 0; dc < 16; dc++) qf[dc] = *(const bf16x8*)&qrow[dc * 16];
    }

    f32x16 acc[8];
    #pragma unroll
    for (int i = 0; i < 8; i++)
        #pragma unroll
        for (int j = 0; j < 16; j++) acc[i][j] = 0.f;
    float m = -1e30f, l = 0.f;

    const short* Kb = Kt + (long)(b * NKV + kv) * S_LEN * HD;
    const short* Vb = Vt + (long)(b * NKV + kv) * HD * S_LEN;

    int nt = 2 * qt + 2;
    for (int tt = 0; tt < nt; tt++) {
        int k0 = tt * KVB;
        // ---- stage K tile [32][256] and V^T tile [256][32], swizzled source ----
        #pragma unroll
        for (int c = 0; c < 8; c++) {
            int o  = (w * 8 + c) * 1024 + lane * 16;      // byte offset in Ks
            int key = o >> 9, db = o & 511;
            gload16(Kb + (long)(k0 + key) * HD + (((db ^ ((key & 7) << 4))) >> 1),
                    &Ks[(w * 8 + c) * 512]);
        }
        #pragma unroll
        for (int c = 0; c < 8; c++) {
            int o = (w * 8 + c) * 1024 + lane * 16;       // byte offset in Vs
            int d = o >> 6, kb = o & 63;
            gload16(Vb + (long)d * S_LEN + k0 + (((kb ^ ((d & 3) << 4))) >> 1),
                    &Vs[(w * 8 + c) * 512]);
        }
        __syncthreads();   // drains vmcnt -> tiles visible

        // ---- QK^T (swapped): s = K * Q, D[key][q], lane owns q column ----
        f32x16 s;
        #pragma unroll
        for (int j = 0; j < 16; j++) s[j] = 0.f;
        #pragma unroll
        for (int dc = 0; dc < 16; dc++) {
            int kbyte = (dc * 32 + hi * 16) ^ ((ln & 7) << 4);
            bf16x8 kf = *(const bf16x8*)((const char*)Ks + ln * 512 + kbyte);
            s = __builtin_amdgcn_mfma_f32_32x32x16_bf16(kf, qf[dc], s, 0, 0, 0);
        }

        // ---- mask + online softmax, fully in-register ----
        if (k0 + KVB - 1 > q0) {
            #pragma unroll
            for (int r = 0; r < 16; r++) {
                int key_g = k0 + (r & 3) + 8 * (r >> 2) + 4 * hi;
                if (key_g > qg) s[r] = -1e30f;
            }
        }
        float mt = s[0];
        #pragma unroll
        for (int r = 1; r < 16; r++) mt = fmaxf(mt, s[r]);
        mt = fmaxf(mt, __shfl_xor(mt, 32));
        float mn = m;
        if (!__all(mt <= m + 8.f)) {           // defer-max (T13)
            mn = fmaxf(m, mt);
            float f = __expf(m - mn);
            m = mn;
            float fr[16];
            #pragma unroll
            for (int r = 0; r < 16; r++)
                fr[r] = bperm((r & 3) + 8 * (r >> 2) + 4 * hi, f);
            #pragma unroll
            for (int i = 0; i < 8; i++)
                #pragma unroll
                for (int r = 0; r < 16; r++) acc[i][r] *= fr[r];
            l *= f;
        }
        float p[16], ps = 0.f;
        #pragma unroll
        for (int r = 0; r < 16; r++) { p[r] = __expf(s[r] - mn); ps += p[r]; }
        ps += __shfl_xor(ps, 32);
        l += ps;

        // ---- P -> bf16 A-fragments via cvt_pk + permlane32_swap (T12) ----
        unsigned pw[8];
        #pragma unroll
        for (int kc = 0; kc < 2; kc++) {
            unsigned X = cvtpk(p[kc * 8 + 0], p[kc * 8 + 1]);
            unsigned Y = cvtpk(p[kc * 8 + 4], p[kc * 8 + 5]);
            unsigned Z = cvtpk(p[kc * 8 + 2], p[kc * 8 + 3]);
            unsigned W = cvtpk(p[kc * 8 + 6], p[kc * 8 + 7]);
            asm volatile("v_permlane32_swap_b32 %0, %1" : "+v"(X), "+v"(Y));
            asm volatile("v_permlane32_swap_b32 %0, %1" : "+v"(Z), "+v"(W));
            pw[kc * 4 + 0] = X; pw[kc * 4 + 1] = Z;
            pw[kc * 4 + 2] = Y; pw[kc * 4 + 3] = W;
        }
        u32x4 w0 = {pw[0], pw[1], pw[2], pw[3]};
        u32x4 w1 = {pw[4], pw[5], pw[6], pw[7]};
        bf16x8 pa0 = __builtin_bit_cast(bf16x8, w0);
        bf16x8 pa1 = __builtin_bit_cast(bf16x8, w1);

        // ---- PV: acc[db] += P * V, D[q][d], lane owns d column ----
        #pragma unroll
        for (int db = 0; db < 8; db++) {
            int drow = db * 32 + ln;
            int sw = (drow & 3) << 4;
            bf16x8 vf0 = *(const bf16x8*)((const char*)Vs + drow * 64 + ((hi * 16) ^ sw));
            bf16x8 vf1 = *(const bf16x8*)((const char*)Vs + drow * 64 + ((32 + hi * 16) ^ sw));
            acc[db] = __builtin_amdgcn_mfma_f32_32x32x16_bf16(pa0, vf0, acc[db], 0, 0, 0);
            acc[db] = __builtin_amdgcn_mfma_f32_32x32x16_bf16(pa1, vf1, acc[db], 0, 0, 0);
        }
        __syncthreads();   // all reads done before next tile's staging
    }

    // ---- epilogue: O[q][d] = acc / l ----
    float linv = 1.f / l;
    float lr[16];
    #pragma unroll
    for (int r = 0; r < 16; r++)
        lr[r] = bperm((r & 3) + 8 * (r >> 2) + 4 * hi, linv);
    #pragma unroll
    for (int db = 0; db < 8; db++)
        #pragma unroll
        for (int r = 0; r < 16; r++) {
            int qrow = q0 + (r & 3) + 8 * (r >> 2) + 4 * hi;
            O[(long)(b * S_LEN + qrow) * 2048 + h * HD + db * 32 + ln] =
                f2bf(acc[db][r] * lr[r]);
        }
}

extern "C" void kernel_launch(void* const* d_in, const int* in_sizes, int n_in,
                              void* d_out, int out_size, void* d_ws, size_t ws_size,
                              hipStream_t stream) {
    const float* x    = (const float*)d_in[0];
    const float* cosb = (const float*)d_in[1];
    const float* sinb = (const float*)d_in[2];
    // d_in[3] = mask: equivalent to causal; computed analytically in-kernel
    const float* wq   = (const float*)d_in[4];
    const float* wk   = (const float*)d_in[5];
    const float* wv   = (const float*)d_in[6];
    const float* wo   = (const float*)d_in[7];
    const float* qnw  = (const float*)d_in[8];
    const float* knw  = (const float*)d_in[9];
    float* out = (float*)d_out;

    char* ws = (char*)d_ws;
    short* xb  = (short*)(ws + 0);          // 4096x512   bf16
    short* wqb = (short*)(ws + 4194304);    // 512x2048
    short* wkb = (short*)(ws + 6291456);    // 512x512
    short* wvb = (short*)(ws + 6815744);    // 512x512
    short* wob = (short*)(ws + 7340032);    // 2048x512
    short* qf  = (short*)(ws + 9437184);    // 4096x2048 (q raw -> roped in place)
    short* kf  = (short*)(ws + 26214400);   // 4096x512
    short* vf  = (short*)(ws + 30408704);   // 4096x512
    short* kr  = (short*)(ws + 34603008);   // [b][kv][s][d]
    short* vr  = (short*)(ws + 38797312);   // [b][kv][d][s]
    short* ao  = (short*)(ws + 42991616);   // 4096x2048

    cvt_kernel<<<2048, 256, 0, stream>>>(x,  xb,  2097152);
    cvt_kernel<<<1024, 256, 0, stream>>>(wq, wqb, 1048576);
    cvt_kernel<<<256,  256, 0, stream>>>(wk, wkb, 262144);
    cvt_kernel<<<256,  256, 0, stream>>>(wv, wvb, 262144);
    cvt_kernel<<<1024, 256, 0, stream>>>(wo, wob, 1048576);

    gemm_kernel<1><<<dim3(32, 64), 256, 0, stream>>>(xb, wqb, qf, 4096, 2048, 512);
    gemm_kernel<1><<<dim3(8, 64),  256, 0, stream>>>(xb, wkb, kf, 4096, 512, 512);
    gemm_kernel<1><<<dim3(8, 64),  256, 0, stream>>>(xb, wvb, vf, 4096, 512, 512);

    // Q gets the 1/sqrt(256) attention scale folded in for free
    norm_rope_kernel<<<8192, 256, 0, stream>>>(qf, qf, qnw, cosb, sinb, 8,
                                               4194304L, 256L, 2048L, 0.0625f);
    norm_rope_kernel<<<2048, 256, 0, stream>>>(kf, kr, knw, cosb, sinb, 2,
                                               1048576L, 524288L, 256L, 1.0f);
    transpose_v_kernel<<<dim3(32, 4, 4), 256, 0, stream>>>(vf, vr);

    flash_kernel<<<512, 128, 0, stream>>>(qf, kr, vr, ao);

    gemm_kernel<0><<<dim3(8, 64), 256, 0, stream>>>(ao, wob, out, 4096, 512, 2048);
}

// Round 3
// 250.571 us; speedup vs baseline: 1.1402x; 1.1402x over previous
//
#include <hip/hip_runtime.h>

#define S_LEN 2048
#define NHQ 8
#define NKV 2
#define HD 256
#define KVB 32

typedef __attribute__((ext_vector_type(8))) short bf16x8;
typedef __attribute__((ext_vector_type(4))) short bf16x4;
typedef __attribute__((ext_vector_type(4))) float f32x4;
typedef __attribute__((ext_vector_type(16))) float f32x16;
typedef __attribute__((ext_vector_type(4))) unsigned u32x4;

__device__ __forceinline__ short f2bf(float f) {
    unsigned u = __builtin_bit_cast(unsigned, f);
    u += 0x7FFFu + ((u >> 16) & 1u);
    return (short)(u >> 16);
}
__device__ __forceinline__ float bf2f(short s) {
    unsigned u = ((unsigned)(unsigned short)s) << 16;
    return __builtin_bit_cast(float, u);
}
__device__ __forceinline__ unsigned cvtpk(float a, float b) {
    unsigned r;
    asm("v_cvt_pk_bf16_f32 %0, %1, %2" : "=v"(r) : "v"(a), "v"(b));
    return r;
}
__device__ __forceinline__ void gload16(const short* g, short* l) {
    __builtin_amdgcn_global_load_lds((const __attribute__((address_space(1))) unsigned*)g,
                                     (__attribute__((address_space(3))) unsigned*)l, 16, 0, 0);
}
__device__ __forceinline__ float bperm(int srclane, float v) {
    return __builtin_bit_cast(float,
        __builtin_amdgcn_ds_bpermute(srclane * 4, __builtin_bit_cast(int, v)));
}

// ---------------- fp32 -> bf16 convert ----------------
__global__ __launch_bounds__(256) void cvt_kernel(const float* __restrict__ in,
                                                  short* __restrict__ out, int n) {
    int i = (blockIdx.x * 256 + threadIdx.x) * 4;
    if (i + 3 < n) {
        float4 f = *(const float4*)(in + i);
        bf16x4 o;
        o[0] = f2bf(f.x); o[1] = f2bf(f.y); o[2] = f2bf(f.z); o[3] = f2bf(f.w);
        *(bf16x4*)(out + i) = o;
    }
}

// ---------------- fp32 W[K][N] -> bf16 Wt[N][K] (convert + transpose) -------
__global__ __launch_bounds__(256) void wt_kernel(const float* __restrict__ in,
                                                 short* __restrict__ out,
                                                 int K, int N) {
    __shared__ short tile[64][72];
    int n0 = blockIdx.x * 64, k0 = blockIdx.y * 64;
    int t = threadIdx.x;
    #pragma unroll
    for (int i = 0; i < 16; i++) {
        int flat = i * 256 + t; int r = flat >> 6, c = flat & 63;
        tile[r][c] = f2bf(in[(long)(k0 + r) * N + n0 + c]);
    }
    __syncthreads();
    #pragma unroll
    for (int i = 0; i < 16; i++) {
        int flat = i * 256 + t; int r = flat >> 6, c = flat & 63;
        out[(long)(n0 + r) * K + k0 + c] = tile[c][r];
    }
}

// ---------------- m97-style GEMM: C[M][N] = A[M][K] @ Bt[N][K]^T ------------
// 128 x BN tile, BK=32, 4 waves (each 64 x BN/2), global_load_lds staging.
template<int BN, int WRITE_BF16>
__global__ __launch_bounds__(256) void gemm_bt(const short* __restrict__ A,
                                               const short* __restrict__ Bt,
                                               void* __restrict__ Cv,
                                               int M, int N, int K) {
    constexpr int NI = BN / 32;          // B-frags per wave
    __shared__ short As[128 * 32];
    __shared__ short Bs[BN * 32];
    const int t = threadIdx.x;
    const int lane = t & 63, w = t >> 6;
    const int lr = lane & 15, lg = lane >> 4;
    const int m0 = blockIdx.y * 128, n0 = blockIdx.x * BN;
    const int wm = (w >> 1) * 64, wn = (w & 1) * (BN / 2);

    f32x4 acc[4][NI];
    #pragma unroll
    for (int i = 0; i < 4; i++)
        #pragma unroll
        for (int j = 0; j < NI; j++) acc[i][j] = (f32x4){0.f, 0.f, 0.f, 0.f};

    for (int k0 = 0; k0 < K; k0 += 32) {
        __syncthreads();
        #pragma unroll
        for (int r = 0; r < 2; r++) {            // A tile: 128x32 = 8 KB
            int sbase = r * 2048 + w * 512;
            int srow = (sbase + lane * 8) >> 5, scol = (sbase + lane * 8) & 31;
            gload16(A + (long)(m0 + srow) * K + k0 + scol, &As[sbase]);
        }
        #pragma unroll
        for (int r = 0; r < BN / 64; r++) {      // B tile: BNx32
            int sbase = r * 2048 + w * 512;
            int srow = (sbase + lane * 8) >> 5, scol = (sbase + lane * 8) & 31;
            gload16(Bt + (long)(n0 + srow) * K + k0 + scol, &Bs[sbase]);
        }
        __syncthreads();
        bf16x8 af[4], bfr[NI];
        #pragma unroll
        for (int mi = 0; mi < 4; mi++)
            af[mi] = *(const bf16x8*)&As[(wm + mi * 16 + lr) * 32 + lg * 8];
        #pragma unroll
        for (int ni = 0; ni < NI; ni++)
            bfr[ni] = *(const bf16x8*)&Bs[(wn + ni * 16 + lr) * 32 + lg * 8];
        #pragma unroll
        for (int mi = 0; mi < 4; mi++)
            #pragma unroll
            for (int ni = 0; ni < NI; ni++)
                acc[mi][ni] = __builtin_amdgcn_mfma_f32_16x16x32_bf16(af[mi], bfr[ni], acc[mi][ni], 0, 0, 0);
    }
    #pragma unroll
    for (int mi = 0; mi < 4; mi++)
    #pragma unroll
    for (int ni = 0; ni < NI; ni++)
    #pragma unroll
    for (int r = 0; r < 4; r++) {
        long row = m0 + wm + mi * 16 + lg * 4 + r;
        long col = n0 + wn + ni * 16 + lr;
        float v = acc[mi][ni][r];
        if (WRITE_BF16) ((short*)Cv)[row * N + col] = f2bf(v);
        else            ((float*)Cv)[row * N + col] = v;
    }
}

// ---------------- RMSNorm + partial RoPE (+ optional score prescale) --------
__global__ __launch_bounds__(256) void norm_rope_kernel(
    const short* __restrict__ in, short* __restrict__ out,
    const float* __restrict__ w, const float* __restrict__ cosb,
    const float* __restrict__ sinb, int H, long ob, long oh, long os,
    float scale) {
    int vec = blockIdx.x * 4 + (threadIdx.x >> 6);
    int lane = threadIdx.x & 63;
    int token = vec / H, head = vec % H;
    int b = token / S_LEN, s = token % S_LEN;

    bf16x4 xv = *(const bf16x4*)(in + (long)vec * 256 + lane * 4);
    float x0 = bf2f(xv[0]), x1 = bf2f(xv[1]), x2 = bf2f(xv[2]), x3 = bf2f(xv[3]);
    float ss = x0 * x0 + x1 * x1 + x2 * x2 + x3 * x3;
    #pragma unroll
    for (int m = 1; m < 64; m <<= 1) ss += __shfl_xor(ss, m);
    float inv = rsqrtf(ss * (1.f / 256.f) + 1e-6f);

    float4 wv = *(const float4*)(w + lane * 4);
    float y0 = x0 * inv * (1.f + wv.x);
    float y1 = x1 * inv * (1.f + wv.y);
    float y2 = x2 * inv * (1.f + wv.z);
    float y3 = x3 * inv * (1.f + wv.w);

    if (lane < 16) {
        float2 c = *(const float2*)&cosb[s * 32 + lane * 2];
        float2 sn = *(const float2*)&sinb[s * 32 + lane * 2];
        float a0 = y0 * c.x - y1 * sn.x, b0 = y0 * sn.x + y1 * c.x;
        float a1 = y2 * c.y - y3 * sn.y, b1 = y2 * sn.y + y3 * c.y;
        y0 = a0; y1 = b0; y2 = a1; y3 = b1;
    }
    y0 *= scale; y1 *= scale; y2 *= scale; y3 *= scale;
    long oidx = (long)b * ob + (long)head * oh + (long)s * os + lane * 4;
    bf16x4 o; o[0] = f2bf(y0); o[1] = f2bf(y1); o[2] = f2bf(y2); o[3] = f2bf(y3);
    *(bf16x4*)(out + oidx) = o;
}

// ---------------- V transpose: vf[b][s][kv][d] -> vr[b][kv][d][s] ----------------
__global__ __launch_bounds__(256) void transpose_v_kernel(const short* __restrict__ vf,
                                                          short* __restrict__ vr) {
    __shared__ short tile[64][65];
    int s0 = blockIdx.x * 64, d0 = blockIdx.y * 64;
    int bkv = blockIdx.z; int b = bkv >> 1, kv = bkv & 1;
    int t = threadIdx.x;
    #pragma unroll
    for (int i = 0; i < 16; i++) {
        int flat = i * 256 + t; int si = flat >> 6, di = flat & 63;
        tile[si][di] = vf[(long)(b * S_LEN + s0 + si) * 512 + kv * 256 + d0 + di];
    }
    __syncthreads();
    #pragma unroll
    for (int i = 0; i < 16; i++) {
        int flat = i * 256 + t; int di = flat >> 6, si = flat & 63;
        vr[(long)(bkv * 256 + d0 + di) * S_LEN + s0 + si] = tile[si][di];
    }
}

// ---------------- flash attention: 2-wave, dbuf LDS, 2-phase pipeline -------
// Scores pre-scaled by 1/16 (folded into Q).
__global__ __launch_bounds__(128) void flash_kernel(const short* __restrict__ Q,
                                                    const short* __restrict__ Kt,
                                                    const short* __restrict__ Vt,
                                                    short* __restrict__ O) {
    __shared__ short Ks[2][KVB * 256];   // [key][d] rows 512B, byte ^= (key&7)<<4
    __shared__ short Vs[2][256 * KVB];   // [d][key] rows 64B,  byte ^= (d&3)<<4

    int idx = blockIdx.x;
    // heavy-first / pair-balanced mapping: first 256 blocks qt=31..16, rest qt=0..15
    int qt = (idx < 256) ? (31 - (idx >> 4)) : ((idx - 256) >> 4);
    int bh = idx & 15, h = bh & 7, b = bh >> 3;
    int kv = h >> 2;
    int t = threadIdx.x, lane = t & 63, w = t >> 6;
    int ln = lane & 31, hi = lane >> 5;
    int q0 = qt * 64 + w * 32;
    int qg = q0 + ln;                        // this lane's q row (score column)

    const short* Kb = Kt + (long)(b * NKV + kv) * S_LEN * HD;
    const short* Vb = Vt + (long)(b * NKV + kv) * HD * S_LEN;

    // Q fragments in registers: Q[q=ln][dc*16 + hi*8 + e]
    bf16x8 qf[16];
    {
        const short* qrow = Q + ((long)(b * S_LEN + qg) * NHQ + h) * HD + hi * 8;
        #pragma unroll
        for (int dc = 0; dc < 16; dc++) qf[dc] = *(const bf16x8*)&qrow[dc * 16];
    }

    f32x16 acc[8];
    #pragma unroll
    for (int i = 0; i < 8; i++)
        #pragma unroll
        for (int j = 0; j < 16; j++) acc[i][j] = 0.f;
    float m = -1e30f, l = 0.f;

    int nt = 2 * qt + 2;

    // ---- staging helper (issues 16 global_load_lds per thread) ----
    auto stage = [&](int buf, int tile) {
        int k0 = tile * KVB;
        #pragma unroll
        for (int c = 0; c < 8; c++) {
            int o = (w * 8 + c) * 1024 + lane * 16;       // byte offset in Ks
            int key = o >> 9, db = o & 511;
            gload16(Kb + (long)(k0 + key) * HD + ((db ^ ((key & 7) << 4)) >> 1),
                    &Ks[buf][(w * 8 + c) * 512]);
        }
        #pragma unroll
        for (int c = 0; c < 8; c++) {
            int o = (w * 8 + c) * 1024 + lane * 16;       // byte offset in Vs
            int d = o >> 6, kb = o & 63;
            gload16(Vb + (long)d * S_LEN + k0 + ((kb ^ ((d & 3) << 4)) >> 1),
                    &Vs[buf][(w * 8 + c) * 512]);
        }
    };

    stage(0, 0);
    __syncthreads();                    // buf0 ready
    int cur = 0;

    for (int tt = 0; tt < nt; tt++) {
        int k0 = tt * KVB;
        if (tt + 1 < nt) stage(cur ^ 1, tt + 1);   // prefetch next tile

        // ---- QK^T (swapped): s = K * Q, D[key][q], lane owns q column ----
        f32x16 s;
        #pragma unroll
        for (int j = 0; j < 16; j++) s[j] = 0.f;
        __builtin_amdgcn_s_setprio(1);
        #pragma unroll
        for (int dc = 0; dc < 16; dc++) {
            int kbyte = (dc * 32 + hi * 16) ^ ((ln & 7) << 4);
            bf16x8 kf = *(const bf16x8*)((const char*)Ks[cur] + ln * 512 + kbyte);
            s = __builtin_amdgcn_mfma_f32_32x32x16_bf16(kf, qf[dc], s, 0, 0, 0);
        }
        __builtin_amdgcn_s_setprio(0);

        // ---- mask + online softmax, fully in-register ----
        if (k0 + KVB - 1 > q0) {
            #pragma unroll
            for (int r = 0; r < 16; r++) {
                int key_g = k0 + (r & 3) + 8 * (r >> 2) + 4 * hi;
                if (key_g > qg) s[r] = -1e30f;
            }
        }
        float mt = s[0];
        #pragma unroll
        for (int r = 1; r < 16; r++) mt = fmaxf(mt, s[r]);
        mt = fmaxf(mt, __shfl_xor(mt, 32));
        float mn = m;
        if (!__all(mt <= m + 8.f)) {           // defer-max (T13)
            mn = fmaxf(m, mt);
            float f = __expf(m - mn);
            m = mn;
            float fr[16];
            #pragma unroll
            for (int r = 0; r < 16; r++)
                fr[r] = bperm((r & 3) + 8 * (r >> 2) + 4 * hi, f);
            #pragma unroll
            for (int i = 0; i < 8; i++)
                #pragma unroll
                for (int r = 0; r < 16; r++) acc[i][r] *= fr[r];
            l *= f;
        }
        float p[16], ps = 0.f;
        #pragma unroll
        for (int r = 0; r < 16; r++) { p[r] = __expf(s[r] - mn); ps += p[r]; }
        ps += __shfl_xor(ps, 32);
        l += ps;

        // ---- P -> bf16 A-fragments via cvt_pk + permlane32_swap (T12) ----
        unsigned pw[8];
        #pragma unroll
        for (int kc = 0; kc < 2; kc++) {
            unsigned X = cvtpk(p[kc * 8 + 0], p[kc * 8 + 1]);
            unsigned Y = cvtpk(p[kc * 8 + 4], p[kc * 8 + 5]);
            unsigned Z = cvtpk(p[kc * 8 + 2], p[kc * 8 + 3]);
            unsigned W = cvtpk(p[kc * 8 + 6], p[kc * 8 + 7]);
            asm volatile("v_permlane32_swap_b32 %0, %1" : "+v"(X), "+v"(Y));
            asm volatile("v_permlane32_swap_b32 %0, %1" : "+v"(Z), "+v"(W));
            pw[kc * 4 + 0] = X; pw[kc * 4 + 1] = Z;
            pw[kc * 4 + 2] = Y; pw[kc * 4 + 3] = W;
        }
        u32x4 w0 = {pw[0], pw[1], pw[2], pw[3]};
        u32x4 w1 = {pw[4], pw[5], pw[6], pw[7]};
        bf16x8 pa0 = __builtin_bit_cast(bf16x8, w0);
        bf16x8 pa1 = __builtin_bit_cast(bf16x8, w1);

        // ---- PV: acc[db] += P * V, D[q][d], lane owns d column ----
        __builtin_amdgcn_s_setprio(1);
        #pragma unroll
        for (int db = 0; db < 8; db++) {
            int drow = db * 32 + ln;
            int sw = (drow & 3) << 4;
            bf16x8 vf0 = *(const bf16x8*)((const char*)Vs[cur] + drow * 64 + ((hi * 16) ^ sw));
            bf16x8 vf1 = *(const bf16x8*)((const char*)Vs[cur] + drow * 64 + ((32 + hi * 16) ^ sw));
            acc[db] = __builtin_amdgcn_mfma_f32_32x32x16_bf16(pa0, vf0, acc[db], 0, 0, 0);
            acc[db] = __builtin_amdgcn_mfma_f32_32x32x16_bf16(pa1, vf1, acc[db], 0, 0, 0);
        }
        __builtin_amdgcn_s_setprio(0);

        __syncthreads();   // staged loads landed; all waves done with buf cur
        cur ^= 1;
    }

    // ---- epilogue: O[q][d] = acc / l ----
    float linv = 1.f / l;
    float lr[16];
    #pragma unroll
    for (int r = 0; r < 16; r++)
        lr[r] = bperm((r & 3) + 8 * (r >> 2) + 4 * hi, linv);
    #pragma unroll
    for (int db = 0; db < 8; db++)
        #pragma unroll
        for (int r = 0; r < 16; r++) {
            int qrow = q0 + (r & 3) + 8 * (r >> 2) + 4 * hi;
            O[(long)(b * S_LEN + qrow) * 2048 + h * HD + db * 32 + ln] =
                f2bf(acc[db][r] * lr[r]);
        }
}

extern "C" void kernel_launch(void* const* d_in, const int* in_sizes, int n_in,
                              void* d_out, int out_size, void* d_ws, size_t ws_size,
                              hipStream_t stream) {
    const float* x    = (const float*)d_in[0];
    const float* cosb = (const float*)d_in[1];
    const float* sinb = (const float*)d_in[2];
    // d_in[3] = mask: equivalent to causal; computed analytically in-kernel
    const float* wq   = (const float*)d_in[4];
    const float* wk   = (const float*)d_in[5];
    const float* wv   = (const float*)d_in[6];
    const float* wo   = (const float*)d_in[7];
    const float* qnw  = (const float*)d_in[8];
    const float* knw  = (const float*)d_in[9];
    float* out = (float*)d_out;

    char* ws = (char*)d_ws;
    short* xb  = (short*)(ws + 0);          // 4096x512   bf16
    short* wqt = (short*)(ws + 4194304);    // 2048x512   (transposed)
    short* wkt = (short*)(ws + 6291456);    // 512x512    (transposed)
    short* wvt = (short*)(ws + 6815744);    // 512x512    (transposed)
    short* wot = (short*)(ws + 7340032);    // 512x2048   (transposed)
    short* qf  = (short*)(ws + 9437184);    // 4096x2048 (q raw -> roped in place)
    short* kf  = (short*)(ws + 26214400);   // 4096x512
    short* vf  = (short*)(ws + 30408704);   // 4096x512
    short* kr  = (short*)(ws + 34603008);   // [b][kv][s][d]
    short* vr  = (short*)(ws + 38797312);   // [b][kv][d][s]
    short* ao  = (short*)(ws + 42991616);   // 4096x2048

    cvt_kernel<<<2048, 256, 0, stream>>>(x, xb, 2097152);
    wt_kernel<<<dim3(32, 8),  256, 0, stream>>>(wq, wqt, 512, 2048);
    wt_kernel<<<dim3(8, 8),   256, 0, stream>>>(wk, wkt, 512, 512);
    wt_kernel<<<dim3(8, 8),   256, 0, stream>>>(wv, wvt, 512, 512);
    wt_kernel<<<dim3(8, 32),  256, 0, stream>>>(wo, wot, 2048, 512);

    gemm_bt<128, 1><<<dim3(16, 32), 256, 0, stream>>>(xb, wqt, qf, 4096, 2048, 512);
    gemm_bt<64, 1><<<dim3(8, 32),   256, 0, stream>>>(xb, wkt, kf, 4096, 512, 512);
    gemm_bt<64, 1><<<dim3(8, 32),   256, 0, stream>>>(xb, wvt, vf, 4096, 512, 512);

    // Q gets the 1/sqrt(256) attention scale folded in for free
    norm_rope_kernel<<<8192, 256, 0, stream>>>(qf, qf, qnw, cosb, sinb, 8,
                                               4194304L, 256L, 2048L, 0.0625f);
    norm_rope_kernel<<<2048, 256, 0, stream>>>(kf, kr, knw, cosb, sinb, 2,
                                               1048576L, 524288L, 256L, 1.0f);
    transpose_v_kernel<<<dim3(32, 4, 4), 256, 0, stream>>>(vf, vr);

    flash_kernel<<<512, 128, 0, stream>>>(qf, kr, vr, ao);

    gemm_bt<64, 0><<<dim3(8, 32), 256, 0, stream>>>(ao, wot, out, 4096, 512, 2048);
}